// Round 1
// baseline (206.042 us; speedup 1.0000x reference)
//
#include <hip/hip_runtime.h>

#define B_ 32
#define N_ 4096
#define C_ 16
#define D_ 256
#define NSPLIT 16
#define ROWS (N_ / NSPLIT)   // 256 rows per block
#define RPW  (ROWS / 4)      // 64 rows per wave
#define NGRP (RPW / 4)       // 16 groups of 4 rows per wave

// ---------------- Stage 1: deep-ring partial sums -> ws (no atomics) -------
// One wave = one full row of D (64 lanes x float4). Ring of 8 rows in
// flight: consume row R, immediately reissue its slot for row R+8 ->
// ~8.25 KB outstanding per wave. NSPLIT=16 -> 512 blocks = 2 blocks/CU
// (8 waves/CU): Little's law needs only ~9 KB/CU outstanding to saturate
// HBM share; we have 8 waves x 8.25 KB = 66 KB. launch_bounds(256,2)
// relaxes the VGPR cap to 256 so the 17x float4 acc + 8-deep ring
// (~120 VGPRs) schedules without pressure. Masks: one 64-lane r-load
// covers a 4-row group; ballot -> wave-uniform 16-bit masks; accumulation
// acc[c] += v * m with m in {0,1} (scalar select feeding FMA, no
// divergence). Special (all-below) row -> 17th register accumulator.
__global__ __launch_bounds__(256, 2)
void tf_stage1(const float* __restrict__ r,
               const float* __restrict__ v,
               float* __restrict__ ws) {
    const int b     = blockIdx.x >> 4;           // / NSPLIT
    const int chunk = blockIdx.x & (NSPLIT - 1);
    const int tid   = threadIdx.x;
    const int wave  = tid >> 6;
    const int lane  = tid & 63;
    const int d4    = lane << 2;

    const float* __restrict__ rb = r + (size_t)b * N_ * C_;
    const float* __restrict__ vp = v + (size_t)b * N_ * D_;

    float4 acc[17];                              // [16] = special (all-below)
#pragma unroll
    for (int c = 0; c < 17; ++c) acc[c] = make_float4(0.f, 0.f, 0.f, 0.f);

    const int base = chunk * ROWS + wave * RPW;  // 64 consecutive rows
    const float* __restrict__ rptr = rb + (size_t)base * C_ + lane;
    const float* __restrict__ vptr = vp + (size_t)base * D_ + d4;

    // ---- prologue: r for groups 0,1 first (ballot waits only on these),
    // then the first 8 v rows into the ring
    float rv0 = rptr[0];
    float rv1 = rptr[64];                        // group 1 (rows 4..7)
    float4 ring[8];
#pragma unroll
    for (int s = 0; s < 8; ++s)
        ring[s] = *(const float4*)(vptr + (size_t)s * D_);

#define ACCROW(VV, MASK)                                       \
    {                                                          \
        const unsigned _m = (MASK);                            \
        _Pragma("unroll")                                      \
        for (int c = 0; c < 16; ++c) {                         \
            const float m = (_m & (1u << c)) ? 1.0f : 0.0f;    \
            acc[c].x += (VV).x * m;                            \
            acc[c].y += (VV).y * m;                            \
            acc[c].z += (VV).z * m;                            \
            acc[c].w += (VV).w * m;                            \
        }                                                      \
        const float ms = (_m == 0u) ? 1.0f : 0.0f;             \
        acc[16].x += (VV).x * ms; acc[16].y += (VV).y * ms;    \
        acc[16].z += (VV).z * ms; acc[16].w += (VV).w * ms;    \
    }

#pragma unroll
    for (int g = 0; g < NGRP; ++g) {
        // consume this group's r (loaded 2 groups ago), reissue its slot
        const float rvc = (g & 1) ? rv1 : rv0;
        const unsigned long long bal = __ballot(rvc >= 0.5f);
        if (g + 2 < NGRP) {
            const float rnew = rptr[(size_t)(g + 2) * 64];
            if (g & 1) rv1 = rnew; else rv0 = rnew;
        }
#pragma unroll
        for (int rr = 0; rr < 4; ++rr) {
            const int row  = 4 * g + rr;
            const int slot = row & 7;
            const float4 vv = ring[slot];        // consume (vmcnt wait here)
            if (row + 8 < RPW)                   // reissue slot for row+8
                ring[slot] = *(const float4*)(vptr + (size_t)(row + 8) * D_);
            const unsigned mm = (unsigned)(bal >> (16 * rr)) & 0xFFFFu;
            ACCROW(vv, mm);
        }
    }

    // ---- cross-wave reduction in LDS (wave0 stores, waves 1..3 accumulate)
    __shared__ float4 lds4[17 * 64];    // 17 KiB
    if (wave == 0) {
#pragma unroll
        for (int c = 0; c < 17; ++c) lds4[c * 64 + lane] = acc[c];
    }
    __syncthreads();
    for (int w = 1; w < 4; ++w) {
        if (wave == w) {
#pragma unroll
            for (int c = 0; c < 17; ++c) {
                float4 t = lds4[c * 64 + lane];
                t.x += acc[c].x; t.y += acc[c].y;
                t.z += acc[c].z; t.w += acc[c].w;
                lds4[c * 64 + lane] = t;
            }
        }
        __syncthreads();
    }

    // ---- coalesced float4 partial store: ws[blk][17][256] (1088 float4)
    float4* __restrict__ wsb = (float4*)(ws + (size_t)blockIdx.x * 17 * D_);
#pragma unroll
    for (int i = 0; i < 4; ++i)
        wsb[i * 256 + tid] = lds4[i * 256 + tid];
    if (tid < 64)
        wsb[1024 + tid] = lds4[1024 + tid];
}

// ---------------- Stage 2: reduce 16 chunk-partials per output float4 ------
// One thread = one float4 of out. idx enumerates (b, j, q) contiguously ->
// both ws reads (per k) and the out write are perfectly coalesced. Full
// 16-deep unroll keeps all 16 dwordx4 loads in flight (64 VGPRs of data).
__global__ __launch_bounds__(256, 4)
void tf_stage2(const float4* __restrict__ ws4, float4* __restrict__ out4) {
    const int idx = blockIdx.x * 256 + threadIdx.x;   // 0 .. 34815
    const int b   = idx / 1088;                       // 17 * 64 float4 per b
    const int rem = idx - b * 1088;

    const float4* __restrict__ p = ws4 + (size_t)b * (NSPLIT * 1088) + rem;
    float sx = 0.f, sy = 0.f, sz = 0.f, sw = 0.f;
#pragma unroll
    for (int k = 0; k < NSPLIT; ++k) {
        const float4 t = p[(size_t)k * 1088];
        sx += t.x; sy += t.y; sz += t.z; sw += t.w;
    }
    const float sc = 1.0f / (float)N_;
    out4[idx] = make_float4(sx * sc, sy * sc, sz * sc, sw * sc);
}

extern "C" void kernel_launch(void* const* d_in, const int* in_sizes, int n_in,
                              void* d_out, int out_size, void* d_ws, size_t ws_size,
                              hipStream_t stream) {
    const float* r = (const float*)d_in[0];   // (B,N,C) fp32
    const float* v = (const float*)d_in[1];   // (B,N,D) fp32
    float* out = (float*)d_out;               // (B,C+1,D) fp32
    float* ws  = (float*)d_ws;                // 8.9 MB used

    tf_stage1<<<dim3(B_ * NSPLIT), 256, 0, stream>>>(r, v, ws);
    // B*17*D/4 float4 outputs / 256 threads = 136 blocks
    tf_stage2<<<dim3((B_ * 17 * D_ / 4) / 256), 256, 0, stream>>>(
        (const float4*)ws, (float4*)out);
    // stage2 writes every out element -> no memset of d_out needed
}

// Round 2
// 203.858 us; speedup vs baseline: 1.0107x; 1.0107x over previous
//
#include <hip/hip_runtime.h>

#define B_ 32
#define N_ 4096
#define C_ 16
#define D_ 256
#define NSPLIT 32
#define ROWS (N_ / NSPLIT)   // 128 rows per block
#define RPW  (ROWS / 4)      // 32 rows per wave
#define NGRP (RPW / 4)       // 8 groups of 4 rows per wave

// ---------------- zero-init out (harness poisons d_out each iteration) -----
__global__ __launch_bounds__(256, 8)
void tf_zero(float4* __restrict__ out4) {
    out4[blockIdx.x * 256 + threadIdx.x] = make_float4(0.f, 0.f, 0.f, 0.f);
}

// ---------------- Stage 1: deep-ring partial sums -> atomicAdd(out) -------
// Geometry reverted to the measured-best 200.7us config: NSPLIT=32,
// 1024 blocks = 4 blocks/CU (16 waves/CU), launch_bounds(256,4).
// One wave = one full row of D (64 lanes x float4). Ring of 8 rows in
// flight: consume row R, immediately reissue its slot for row R+8 ->
// 8 KB outstanding per wave, 128 KB/CU. Masks: one 64-lane r-load covers
// a 4-row group; ballot -> wave-uniform 16-bit masks in SGPRs;
// accumulation acc[c] += v * m with m in {0,1} (scalar select feeding
// FMA, no divergence). Special (all-below) row -> 17th accumulator.
// NEW vs 200.7us version: epilogue atomicAdds the block's LDS-reduced
// partial (pre-scaled by 1/N) straight into out -- removes the 17.8 MB
// ws write, the 17.8 MB stage2 read, and the stage2 launch. 4.45M
// fp32 atomics onto 0.53 MB -> L2/L3-resident RMW, ~32 hits/address.
__global__ __launch_bounds__(256, 4)
void tf_stage1(const float* __restrict__ r,
               const float* __restrict__ v,
               float* __restrict__ out) {
    const int b     = blockIdx.x >> 5;           // / NSPLIT
    const int chunk = blockIdx.x & (NSPLIT - 1);
    const int tid   = threadIdx.x;
    const int wave  = tid >> 6;
    const int lane  = tid & 63;
    const int d4    = lane << 2;

    const float* __restrict__ rb = r + (size_t)b * N_ * C_;
    const float* __restrict__ vp = v + (size_t)b * N_ * D_;

    float4 acc[17];                              // [16] = special (all-below)
#pragma unroll
    for (int c = 0; c < 17; ++c) acc[c] = make_float4(0.f, 0.f, 0.f, 0.f);

    const int base = chunk * ROWS + wave * RPW;  // 32 consecutive rows
    const float* __restrict__ rptr = rb + (size_t)base * C_ + lane;
    const float* __restrict__ vptr = vp + (size_t)base * D_ + d4;

    // ---- prologue: r for groups 0,1 first (ballot waits only on these),
    // then the first 8 v rows into the ring
    float rv0 = rptr[0];
    float rv1 = rptr[64];                        // group 1 (rows 4..7)
    float4 ring[8];
#pragma unroll
    for (int s = 0; s < 8; ++s)
        ring[s] = *(const float4*)(vptr + (size_t)s * D_);

#define ACCROW(VV, MASK)                                       \
    {                                                          \
        const unsigned _m = (MASK);                            \
        _Pragma("unroll")                                      \
        for (int c = 0; c < 16; ++c) {                         \
            const float m = (_m & (1u << c)) ? 1.0f : 0.0f;    \
            acc[c].x += (VV).x * m;                            \
            acc[c].y += (VV).y * m;                            \
            acc[c].z += (VV).z * m;                            \
            acc[c].w += (VV).w * m;                            \
        }                                                      \
        const float ms = (_m == 0u) ? 1.0f : 0.0f;             \
        acc[16].x += (VV).x * ms; acc[16].y += (VV).y * ms;    \
        acc[16].z += (VV).z * ms; acc[16].w += (VV).w * ms;    \
    }

#pragma unroll
    for (int g = 0; g < NGRP; ++g) {
        // consume this group's r (loaded 2 groups ago), reissue its slot
        const float rvc = (g & 1) ? rv1 : rv0;
        const unsigned long long bal = __ballot(rvc >= 0.5f);
        if (g + 2 < NGRP) {
            const float rnew = rptr[(size_t)(g + 2) * 64];
            if (g & 1) rv1 = rnew; else rv0 = rnew;
        }
#pragma unroll
        for (int rr = 0; rr < 4; ++rr) {
            const int row  = 4 * g + rr;
            const int slot = row & 7;
            const float4 vv = ring[slot];        // consume (vmcnt wait here)
            if (row + 8 < RPW)                   // reissue slot for row+8
                ring[slot] = *(const float4*)(vptr + (size_t)(row + 8) * D_);
            const unsigned mm = (unsigned)(bal >> (16 * rr)) & 0xFFFFu;
            ACCROW(vv, mm);
        }
    }

    // ---- cross-wave reduction in LDS (wave0 stores, waves 1..3 accumulate)
    __shared__ float4 lds4[17 * 64];    // 17 KiB
    if (wave == 0) {
#pragma unroll
        for (int c = 0; c < 17; ++c) lds4[c * 64 + lane] = acc[c];
    }
    __syncthreads();
    for (int w = 1; w < 4; ++w) {
        if (wave == w) {
#pragma unroll
            for (int c = 0; c < 17; ++c) {
                float4 t = lds4[c * 64 + lane];
                t.x += acc[c].x; t.y += acc[c].y;
                t.z += acc[c].z; t.w += acc[c].w;
                lds4[c * 64 + lane] = t;
            }
        }
        __syncthreads();
    }

    // ---- atomic accumulate into out: 17 coalesced atomic dwords / thread
    const float sc = 1.0f / (float)N_;
    float* __restrict__ outb = out + (size_t)b * 17 * D_;
    const float* lf = (const float*)lds4;
#pragma unroll
    for (int c = 0; c < 17; ++c)
        atomicAdd(&outb[c * D_ + tid], lf[c * 256 + tid] * sc);
}

extern "C" void kernel_launch(void* const* d_in, const int* in_sizes, int n_in,
                              void* d_out, int out_size, void* d_ws, size_t ws_size,
                              hipStream_t stream) {
    const float* r = (const float*)d_in[0];   // (B,N,C) fp32
    const float* v = (const float*)d_in[1];   // (B,N,D) fp32
    float* out = (float*)d_out;               // (B,C+1,D) fp32
    (void)d_ws; (void)ws_size;                // ws unused now

    // out = B*17*D floats = 34816 float4 = 136 blocks of 256
    tf_zero<<<dim3((B_ * 17 * D_ / 4) / 256), 256, 0, stream>>>((float4*)out);
    tf_stage1<<<dim3(B_ * NSPLIT), 256, 0, stream>>>(r, v, out);
}